// Round 1
// baseline (653.734 us; speedup 1.0000x reference)
//
#include <hip/hip_runtime.h>
#include <hip/hip_bf16.h>
#include <math.h>

// MessagePassingLayer on MI355X.
// Pipeline: memset(upd) ; prep_weights ; gemm(src_h) ; gemm(dst_h) ;
//           edge_fused (gate+MLP+LN+scatter) ; gemm(out).
// All heavy GEMMs use v_mfma_f32_16x16x32_bf16 with fp32 accumulation.

typedef __bf16 bf16x8 __attribute__((ext_vector_type(8)));
typedef float floatx4 __attribute__((ext_vector_type(4)));

#define LN_EPS 1e-5f

__device__ __forceinline__ unsigned short f2bf(float x) {
  // round-to-nearest-even fp32 -> bf16 (inputs are finite; no NaN guard needed)
  unsigned int u = __float_as_uint(x);
  u = u + 0x7fffu + ((u >> 16) & 1u);
  return (unsigned short)(u >> 16);
}

__device__ __forceinline__ float geluf(float x) {
  // exact erf gelu, matches jax.nn.gelu(approximate=False)
  return 0.5f * x * (1.0f + erff(x * 0.70710678118654752f));
}

// ---------------------------------------------------------------------------
// prep: convert+transpose 9 [128,128] fp32 weights to bf16 [n][k] (B-operand
// layout: row n contiguous in k so fragments are ds_read_b128-able).
// slots: 0 WsrcT 1 WdstT 2 W1aT 3 W1bT 4 W2T 5 W3T 6 Wg1aT 7 Wg1bT 8 WoutT
// ---------------------------------------------------------------------------
__global__ void prep_weights(const float* w0, const float* w1, const float* w2,
                             const float* w3, const float* w4, const float* w5,
                             const float* w6, const float* w7, const float* w8,
                             unsigned short* out) {
  const float* srcs[9] = {w0, w1, w2, w3, w4, w5, w6, w7, w8};
  const float* src = srcs[blockIdx.x];
  unsigned short* dst = out + blockIdx.x * 16384;
  for (int idx = threadIdx.x; idx < 16384; idx += 256) {
    int n = idx >> 7, k = idx & 127;
    dst[idx] = f2bf(src[k * 128 + n]);
  }
}

// ---------------------------------------------------------------------------
// C[M,128] = A[M,128](fp32) @ W[128,128] + bias ; out bf16 or fp32.
// Block = 256 thr / 4 waves, 64-row tile; wave w owns cols [32w,32w+32).
// ---------------------------------------------------------------------------
template <bool OUT_BF16>
__global__ __launch_bounds__(256) void gemm128(
    const float* __restrict__ A, const unsigned short* __restrict__ Bt,
    const float* __restrict__ bias, void* __restrict__ Cv, int M) {
  __shared__ __align__(16) unsigned short sA[64][136];   // pad 136: odd*16B stride
  __shared__ __align__(16) unsigned short sW[128][136];
  int tid = threadIdx.x;
  int r0 = blockIdx.x * 64;

  {  // stage A (fp32 -> bf16 on the fly), 4 threads per row
    int r = tid >> 2, seg = tid & 3;
    int row = r0 + r;
    const float* src = A + (long long)row * 128;
    for (int it = 0; it < 4; ++it) {
      int c = (seg * 4 + it) * 8;
      unsigned short tmp[8];
      if (row < M) {
        float4 f0 = *(const float4*)(src + c);
        float4 f1 = *(const float4*)(src + c + 4);
        tmp[0] = f2bf(f0.x); tmp[1] = f2bf(f0.y); tmp[2] = f2bf(f0.z); tmp[3] = f2bf(f0.w);
        tmp[4] = f2bf(f1.x); tmp[5] = f2bf(f1.y); tmp[6] = f2bf(f1.z); tmp[7] = f2bf(f1.w);
      } else {
        for (int j = 0; j < 8; ++j) tmp[j] = 0;
      }
      *(int4*)&sA[r][c] = *(const int4*)tmp;
    }
  }
  for (int it = 0; it < 8; ++it) {  // stage W (already bf16 [n][k])
    int c = tid + it * 256; int row = c >> 4; int cw = (c & 15) * 8;
    *(int4*)&sW[row][cw] = *(const int4*)(Bt + row * 128 + cw);
  }
  __syncthreads();

  int w = tid >> 6, lane = tid & 63, lr = lane & 15, q = lane >> 4;
  floatx4 acc[4][2];
  for (int mb = 0; mb < 4; ++mb)
    for (int nb = 0; nb < 2; ++nb) acc[mb][nb] = (floatx4){0.f, 0.f, 0.f, 0.f};

  for (int kb = 0; kb < 4; ++kb) {
    int k = kb * 32 + q * 8;
    bf16x8 b0 = *(const bf16x8*)&sW[32 * w + lr][k];
    bf16x8 b1 = *(const bf16x8*)&sW[32 * w + 16 + lr][k];
    for (int mb = 0; mb < 4; ++mb) {
      bf16x8 a = *(const bf16x8*)&sA[16 * mb + lr][k];
      acc[mb][0] = __builtin_amdgcn_mfma_f32_16x16x32_bf16(a, b0, acc[mb][0], 0, 0, 0);
      acc[mb][1] = __builtin_amdgcn_mfma_f32_16x16x32_bf16(a, b1, acc[mb][1], 0, 0, 0);
    }
  }

  float bv0 = bias[32 * w + lr], bv1 = bias[32 * w + 16 + lr];
  for (int mb = 0; mb < 4; ++mb)
    for (int i = 0; i < 4; ++i) {
      int row = r0 + 16 * mb + 4 * q + i;
      if (row < M) {
        float v0 = acc[mb][0][i] + bv0;
        float v1 = acc[mb][1][i] + bv1;
        long long base = (long long)row * 128 + 32 * w + lr;
        if (OUT_BF16) {
          unsigned short* C = (unsigned short*)Cv;
          C[base] = f2bf(v0);
          C[base + 16] = f2bf(v1);
        } else {
          float* C = (float*)Cv;
          C[base] = v0;
          C[base + 16] = v1;
        }
      }
    }
}

// ---------------------------------------------------------------------------
// Fused edge kernel: 64 edges/block, 4 waves; wave w owns cols [32w,32w+32).
//   accg = se@Wg1a + de@Wg1b ; gate = sigmoid(gelu(accg+bg1)@Wg2 + bg2)
//   h1 = gelu(se@W1a + de@W1b + b1) ; h2 = gelu(h1@W2 + b2)
//   msg = gate * layernorm(h2@W3 + b3) ; atomic scatter-add into upd[dst]
// ---------------------------------------------------------------------------
__global__ __launch_bounds__(256) void edge_fused(
    const unsigned short* __restrict__ src_h, const unsigned short* __restrict__ dst_h,
    const int* __restrict__ edge_src, const int* __restrict__ edge_dst,
    const unsigned short* __restrict__ wT,
    const float* __restrict__ b1, const float* __restrict__ b2,
    const float* __restrict__ b3, const float* __restrict__ ln_g,
    const float* __restrict__ ln_b, const float* __restrict__ bg1,
    const float* __restrict__ Wg2, const float* __restrict__ bg2,
    float* __restrict__ upd, int E) {
  __shared__ __align__(16) unsigned short sSE[64][136];  // se, later h1
  __shared__ __align__(16) unsigned short sDE[64][136];  // de, later h2
  __shared__ __align__(16) unsigned short sW[128][136];  // current weight
  __shared__ int sDst[64];
  __shared__ float sGate[64];
  __shared__ float sR1[4][64];
  __shared__ float sR2[4][64];

  int tid = threadIdx.x;
  int e0 = blockIdx.x * 64;

  {  // gather se/de rows (bf16, 256B each) — 4 threads per edge row
    int r = tid >> 2, seg = tid & 3;
    int e = e0 + r;
    int ee = (e < E) ? e : (E - 1);
    int es = edge_src[ee], ed = edge_dst[ee];
    if (seg == 0) sDst[r] = (e < E) ? ed : -1;
    const int4* ps = (const int4*)(src_h + (long long)es * 128);
    const int4* pd = (const int4*)(dst_h + (long long)ed * 128);
    for (int it = 0; it < 4; ++it) {
      int cc = seg * 4 + it;
      *(int4*)&sSE[r][cc * 8] = ps[cc];
      *(int4*)&sDE[r][cc * 8] = pd[cc];
    }
  }

  auto loadW = [&](int m) {
    const unsigned short* W = wT + m * 16384;
    for (int it = 0; it < 8; ++it) {
      int c = tid + it * 256; int row = c >> 4; int cw = (c & 15) * 8;
      *(int4*)&sW[row][cw] = *(const int4*)(W + row * 128 + cw);
    }
  };

  int w = tid >> 6, lane = tid & 63, lr = lane & 15, q = lane >> 4;

  auto mfmaA = [&](const unsigned short (*Abuf)[136], floatx4 (&acc)[4][2]) {
    for (int kb = 0; kb < 4; ++kb) {
      int k = kb * 32 + q * 8;
      bf16x8 b0 = *(const bf16x8*)&sW[32 * w + lr][k];
      bf16x8 b1 = *(const bf16x8*)&sW[32 * w + 16 + lr][k];
      for (int mb = 0; mb < 4; ++mb) {
        bf16x8 a = *(const bf16x8*)&Abuf[16 * mb + lr][k];
        acc[mb][0] = __builtin_amdgcn_mfma_f32_16x16x32_bf16(a, b0, acc[mb][0], 0, 0, 0);
        acc[mb][1] = __builtin_amdgcn_mfma_f32_16x16x32_bf16(a, b1, acc[mb][1], 0, 0, 0);
      }
    }
  };

  // ---- gate path ----
  loadW(6);  // Wg1aT  (disjoint LDS regions; no hazard with gather)
  __syncthreads();
  floatx4 accg[4][2];
  for (int mb = 0; mb < 4; ++mb)
    for (int nb = 0; nb < 2; ++nb) accg[mb][nb] = (floatx4){0.f, 0.f, 0.f, 0.f};
  mfmaA(sSE, accg);
  __syncthreads();
  loadW(7);  // Wg1bT
  __syncthreads();
  mfmaA(sDE, accg);

  {
    float wg0 = Wg2[32 * w + lr], wg1 = Wg2[32 * w + 16 + lr];
    float bgv0 = bg1[32 * w + lr], bgv1 = bg1[32 * w + 16 + lr];
    for (int mb = 0; mb < 4; ++mb)
      for (int i = 0; i < 4; ++i) {
        float p = geluf(accg[mb][0][i] + bgv0) * wg0 +
                  geluf(accg[mb][1][i] + bgv1) * wg1;
        p += __shfl_xor(p, 1); p += __shfl_xor(p, 2);
        p += __shfl_xor(p, 4); p += __shfl_xor(p, 8);
        if (lr == 0) sR1[w][16 * mb + 4 * q + i] = p;
      }
  }
  __syncthreads();  // gate partials visible; all sW(Wg1b) reads done
  loadW(2);         // W1aT
  if (tid < 64) {
    float g = sR1[0][tid] + sR1[1][tid] + sR1[2][tid] + sR1[3][tid] + bg2[0];
    sGate[tid] = 1.f / (1.f + expf(-g));
  }
  __syncthreads();

  // ---- stage 1 ----
  floatx4 acc1[4][2];
  for (int mb = 0; mb < 4; ++mb)
    for (int nb = 0; nb < 2; ++nb) acc1[mb][nb] = (floatx4){0.f, 0.f, 0.f, 0.f};
  mfmaA(sSE, acc1);
  __syncthreads();  // sSE + sW reads done
  loadW(3);         // W1bT
  __syncthreads();
  mfmaA(sDE, acc1);
  {  // h1 -> sSE (safe: last sSE read was before the loadW(3) barrier)
    float bv0 = b1[32 * w + lr], bv1 = b1[32 * w + 16 + lr];
    for (int mb = 0; mb < 4; ++mb)
      for (int i = 0; i < 4; ++i) {
        int r = 16 * mb + 4 * q + i;
        sSE[r][32 * w + lr] = f2bf(geluf(acc1[mb][0][i] + bv0));
        sSE[r][32 * w + 16 + lr] = f2bf(geluf(acc1[mb][1][i] + bv1));
      }
  }
  __syncthreads();
  loadW(4);  // W2T
  __syncthreads();

  // ---- stage 2 ----
  floatx4 acc2[4][2];
  for (int mb = 0; mb < 4; ++mb)
    for (int nb = 0; nb < 2; ++nb) acc2[mb][nb] = (floatx4){0.f, 0.f, 0.f, 0.f};
  mfmaA(sSE, acc2);
  {  // h2 -> sDE (safe: last sDE read was before the loadW(4) barrier)
    float bv0 = b2[32 * w + lr], bv1 = b2[32 * w + 16 + lr];
    for (int mb = 0; mb < 4; ++mb)
      for (int i = 0; i < 4; ++i) {
        int r = 16 * mb + 4 * q + i;
        sDE[r][32 * w + lr] = f2bf(geluf(acc2[mb][0][i] + bv0));
        sDE[r][32 * w + 16 + lr] = f2bf(geluf(acc2[mb][1][i] + bv1));
      }
  }
  __syncthreads();
  loadW(5);  // W3T
  __syncthreads();

  // ---- stage 3 + layernorm + gate + scatter ----
  floatx4 acc3[4][2];
  for (int mb = 0; mb < 4; ++mb)
    for (int nb = 0; nb < 2; ++nb) acc3[mb][nb] = (floatx4){0.f, 0.f, 0.f, 0.f};
  mfmaA(sDE, acc3);
  {
    float bv0 = b3[32 * w + lr], bv1 = b3[32 * w + 16 + lr];
    for (int mb = 0; mb < 4; ++mb)
      for (int i = 0; i < 4; ++i) {
        float x0 = acc3[mb][0][i] + bv0;
        float x1 = acc3[mb][1][i] + bv1;
        acc3[mb][0][i] = x0; acc3[mb][1][i] = x1;
        float s = x0 + x1, s2 = x0 * x0 + x1 * x1;
        s += __shfl_xor(s, 1); s += __shfl_xor(s, 2);
        s += __shfl_xor(s, 4); s += __shfl_xor(s, 8);
        s2 += __shfl_xor(s2, 1); s2 += __shfl_xor(s2, 2);
        s2 += __shfl_xor(s2, 4); s2 += __shfl_xor(s2, 8);
        if (lr == 0) { sR1[w][16 * mb + 4 * q + i] = s; sR2[w][16 * mb + 4 * q + i] = s2; }
      }
  }
  __syncthreads();
  if (tid < 64) {
    float s = sR1[0][tid] + sR1[1][tid] + sR1[2][tid] + sR1[3][tid];
    float s2 = sR2[0][tid] + sR2[1][tid] + sR2[2][tid] + sR2[3][tid];
    float m = s * (1.f / 128.f);
    float v = s2 * (1.f / 128.f) - m * m;
    sR1[0][tid] = m;
    sR2[0][tid] = rsqrtf(v + LN_EPS);
  }
  __syncthreads();
  {
    float lg0 = ln_g[32 * w + lr], lg1 = ln_g[32 * w + 16 + lr];
    float lb0 = ln_b[32 * w + lr], lb1 = ln_b[32 * w + 16 + lr];
    for (int mb = 0; mb < 4; ++mb)
      for (int i = 0; i < 4; ++i) {
        int r = 16 * mb + 4 * q + i;
        int dst = sDst[r];
        if (dst >= 0) {
          float m = sR1[0][r], rs = sR2[0][r], gt = sGate[r];
          float v0 = ((acc3[mb][0][i] - m) * rs * lg0 + lb0) * gt;
          float v1 = ((acc3[mb][1][i] - m) * rs * lg1 + lb1) * gt;
          float* base = upd + (long long)dst * 128;
          unsafeAtomicAdd(base + 32 * w + lr, v0);        // hw global_atomic_add_f32
          unsafeAtomicAdd(base + 32 * w + 16 + lr, v1);
        }
      }
  }
}

// ---------------------------------------------------------------------------
extern "C" void kernel_launch(void* const* d_in, const int* in_sizes, int n_in,
                              void* d_out, int out_size, void* d_ws, size_t ws_size,
                              hipStream_t stream) {
  const float* feat   = (const float*)d_in[0];
  const int* edge_src = (const int*)d_in[1];
  const int* edge_dst = (const int*)d_in[2];
  const float* W_src = (const float*)d_in[3];  const float* b_src = (const float*)d_in[4];
  const float* W_dst = (const float*)d_in[5];  const float* b_dst = (const float*)d_in[6];
  const float* W1a = (const float*)d_in[7];    const float* W1b = (const float*)d_in[8];
  const float* b1  = (const float*)d_in[9];
  const float* W2  = (const float*)d_in[10];   const float* b2  = (const float*)d_in[11];
  const float* W3  = (const float*)d_in[12];   const float* b3  = (const float*)d_in[13];
  const float* ln_g = (const float*)d_in[14];  const float* ln_b = (const float*)d_in[15];
  const float* Wg1a = (const float*)d_in[16];  const float* Wg1b = (const float*)d_in[17];
  const float* bg1  = (const float*)d_in[18];
  const float* Wg2  = (const float*)d_in[19];  const float* bg2 = (const float*)d_in[20];
  const float* W_out = (const float*)d_in[21]; const float* b_out = (const float*)d_in[22];

  int N = in_sizes[0] / 128;   // 100000
  int E = in_sizes[1];         // 400000

  // workspace layout (bytes): [wT 9*32KB][src_h bf16][dst_h bf16][upd fp32]
  char* ws = (char*)d_ws;
  unsigned short* wT = (unsigned short*)ws;
  size_t off = 9 * 16384 * sizeof(unsigned short);             // 294912
  unsigned short* src_h = (unsigned short*)(ws + off);
  off += (size_t)N * 128 * sizeof(unsigned short);
  unsigned short* dst_h = (unsigned short*)(ws + off);
  off += (size_t)N * 128 * sizeof(unsigned short);
  float* upd = (float*)(ws + off);

  hipMemsetAsync(upd, 0, (size_t)N * 128 * sizeof(float), stream);
  prep_weights<<<9, 256, 0, stream>>>(W_src, W_dst, W1a, W1b, W2, W3, Wg1a, Wg1b,
                                      W_out, wT);
  int mtiles = (N + 63) / 64;
  gemm128<true><<<mtiles, 256, 0, stream>>>(feat, wT + 0 * 16384, b_src, src_h, N);
  gemm128<true><<<mtiles, 256, 0, stream>>>(feat, wT + 1 * 16384, b_dst, dst_h, N);
  edge_fused<<<(E + 63) / 64, 256, 0, stream>>>(src_h, dst_h, edge_src, edge_dst, wT,
                                                b1, b2, b3, ln_g, ln_b, bg1, Wg2, bg2,
                                                upd, E);
  gemm128<false><<<mtiles, 256, 0, stream>>>(upd, wT + 8 * 16384, b_out, d_out, N);
}

// Round 3
// 472.136 us; speedup vs baseline: 1.3846x; 1.3846x over previous
//
#include <hip/hip_runtime.h>
#include <hip/hip_bf16.h>
#include <math.h>

// MessagePassingLayer on MI355X — round 2 (compile fix: cast d_out).
// vs round 1: (a) no LDS weight staging — B-fragments are loaded per-lane
// straight from global (weights are L2-resident, 32KB each); LDS 72->37KB
// lifts edge_fused occupancy 2->4 blocks/CU and cuts barriers 12->7.
// (b) erff gelu -> sigmoid-form tanh approx (~8 VALU vs ~35, no divergence).
// (c) node gemms fused into one kernel (feat read once).

typedef __bf16 bf16x8 __attribute__((ext_vector_type(8)));
typedef float floatx4 __attribute__((ext_vector_type(4)));

#define LN_EPS 1e-5f

__device__ __forceinline__ unsigned short f2bf(float x) {
  unsigned int u = __float_as_uint(x);
  u = u + 0x7fffu + ((u >> 16) & 1u);
  return (unsigned short)(u >> 16);
}

__device__ __forceinline__ float geluf(float x) {
  // tanh-form gelu via sigmoid: 0.5x(1+tanh(a)) = x*sigmoid(2a),
  // 2a = 1.5957691x(1 + 0.044715x^2). |err| vs erf-gelu ~3e-3, well inside
  // the bf16-dominated error budget (round-1 absmax 0.125 vs thr 0.495).
  float t = x * x;
  float u = x * (1.5957691216f + 0.0713548162f * t);
  return x / (1.0f + __expf(-u));
}

// ---------------------------------------------------------------------------
// prep: 9 [128,128] fp32 weights -> bf16 [n][k] (transposed, row-n contiguous
// in k). slots: 0 WsrcT 1 WdstT 2 W1aT 3 W1bT 4 W2T 5 W3T 6 Wg1aT 7 Wg1bT 8 WoutT
// ---------------------------------------------------------------------------
__global__ void prep_weights(const float* w0, const float* w1, const float* w2,
                             const float* w3, const float* w4, const float* w5,
                             const float* w6, const float* w7, const float* w8,
                             unsigned short* out) {
  const float* srcs[9] = {w0, w1, w2, w3, w4, w5, w6, w7, w8};
  const float* src = srcs[blockIdx.x];
  unsigned short* dst = out + blockIdx.x * 16384;
  for (int idx = threadIdx.x; idx < 16384; idx += 256) {
    int n = idx >> 7, k = idx & 127;
    dst[idx] = f2bf(src[k * 128 + n]);
  }
}

// B-fragment loader: wave w, lane (lr,q) needs rows 32w+lr and 32w+16+lr,
// cols kb*32+q*8..+8 of the [n][k] bf16 matrix. 8 x 16B loads from L2.
#define LDB(pB, B)                                              \
  do {                                                          \
    const unsigned short* _p = (pB);                            \
    for (int kb = 0; kb < 4; ++kb) {                            \
      B[0][kb] = *(const bf16x8*)(_p + kb * 32);                \
      B[1][kb] = *(const bf16x8*)(_p + 2048 + kb * 32);         \
    }                                                           \
  } while (0)

// ---------------------------------------------------------------------------
// Fused node GEMM: src_h = feat@Wsrc+b_src, dst_h = feat@Wdst+b_dst (bf16 out).
// 64-row tile, 4 waves; wave w owns cols [32w,32w+32). A staged once in LDS.
// ---------------------------------------------------------------------------
__global__ __launch_bounds__(256, 4) void gemm_node(
    const float* __restrict__ A, const unsigned short* __restrict__ wT,
    const float* __restrict__ b_src, const float* __restrict__ b_dst,
    unsigned short* __restrict__ src_h, unsigned short* __restrict__ dst_h,
    int M) {
  __shared__ __align__(16) unsigned short sA[64][136];
  int tid = threadIdx.x;
  int r0 = blockIdx.x * 64;

  {
    int r = tid >> 2, seg = tid & 3;
    int row = r0 + r;
    const float* src = A + (long long)row * 128;
    for (int it = 0; it < 4; ++it) {
      int c = (seg * 4 + it) * 8;
      unsigned short tmp[8];
      if (row < M) {
        float4 f0 = *(const float4*)(src + c);
        float4 f1 = *(const float4*)(src + c + 4);
        tmp[0] = f2bf(f0.x); tmp[1] = f2bf(f0.y); tmp[2] = f2bf(f0.z); tmp[3] = f2bf(f0.w);
        tmp[4] = f2bf(f1.x); tmp[5] = f2bf(f1.y); tmp[6] = f2bf(f1.z); tmp[7] = f2bf(f1.w);
      } else {
        for (int j = 0; j < 8; ++j) tmp[j] = 0;
      }
      *(int4*)&sA[r][c] = *(const int4*)tmp;
    }
  }
  __syncthreads();

  int w = tid >> 6, lane = tid & 63, lr = lane & 15, q = lane >> 4;
  const unsigned short* pB = wT + (32 * w + lr) * 128 + q * 8;

  bf16x8 B[2][4];
  floatx4 acc[4][2];

  for (int pass = 0; pass < 2; ++pass) {
    LDB(pB + pass * 16384, B);
    for (int mb = 0; mb < 4; ++mb)
      for (int nb = 0; nb < 2; ++nb) acc[mb][nb] = (floatx4){0.f, 0.f, 0.f, 0.f};
    for (int kb = 0; kb < 4; ++kb) {
      int k = kb * 32 + q * 8;
      for (int mb = 0; mb < 4; ++mb) {
        bf16x8 a = *(const bf16x8*)&sA[16 * mb + lr][k];
        acc[mb][0] = __builtin_amdgcn_mfma_f32_16x16x32_bf16(a, B[0][kb], acc[mb][0], 0, 0, 0);
        acc[mb][1] = __builtin_amdgcn_mfma_f32_16x16x32_bf16(a, B[1][kb], acc[mb][1], 0, 0, 0);
      }
    }
    const float* bias = pass ? b_dst : b_src;
    unsigned short* C = pass ? dst_h : src_h;
    float bv0 = bias[32 * w + lr], bv1 = bias[32 * w + 16 + lr];
    for (int mb = 0; mb < 4; ++mb)
      for (int i = 0; i < 4; ++i) {
        int row = r0 + 16 * mb + 4 * q + i;
        if (row < M) {
          long long base = (long long)row * 128 + 32 * w + lr;
          C[base] = f2bf(acc[mb][0][i] + bv0);
          C[base + 16] = f2bf(acc[mb][1][i] + bv1);
        }
      }
  }
}

// ---------------------------------------------------------------------------
// out GEMM: d_out = upd@Wout + b_out (fp32 in, fp32 out)
// ---------------------------------------------------------------------------
__global__ __launch_bounds__(256, 4) void gemm_out(
    const float* __restrict__ A, const unsigned short* __restrict__ Bt,
    const float* __restrict__ bias, float* __restrict__ C, int M) {
  __shared__ __align__(16) unsigned short sA[64][136];
  int tid = threadIdx.x;
  int r0 = blockIdx.x * 64;

  {
    int r = tid >> 2, seg = tid & 3;
    int row = r0 + r;
    const float* src = A + (long long)row * 128;
    for (int it = 0; it < 4; ++it) {
      int c = (seg * 4 + it) * 8;
      unsigned short tmp[8];
      if (row < M) {
        float4 f0 = *(const float4*)(src + c);
        float4 f1 = *(const float4*)(src + c + 4);
        tmp[0] = f2bf(f0.x); tmp[1] = f2bf(f0.y); tmp[2] = f2bf(f0.z); tmp[3] = f2bf(f0.w);
        tmp[4] = f2bf(f1.x); tmp[5] = f2bf(f1.y); tmp[6] = f2bf(f1.z); tmp[7] = f2bf(f1.w);
      } else {
        for (int j = 0; j < 8; ++j) tmp[j] = 0;
      }
      *(int4*)&sA[r][c] = *(const int4*)tmp;
    }
  }
  __syncthreads();

  int w = tid >> 6, lane = tid & 63, lr = lane & 15, q = lane >> 4;
  const unsigned short* pB = Bt + (32 * w + lr) * 128 + q * 8;

  bf16x8 B[2][4];
  LDB(pB, B);
  floatx4 acc[4][2];
  for (int mb = 0; mb < 4; ++mb)
    for (int nb = 0; nb < 2; ++nb) acc[mb][nb] = (floatx4){0.f, 0.f, 0.f, 0.f};
  for (int kb = 0; kb < 4; ++kb) {
    int k = kb * 32 + q * 8;
    for (int mb = 0; mb < 4; ++mb) {
      bf16x8 a = *(const bf16x8*)&sA[16 * mb + lr][k];
      acc[mb][0] = __builtin_amdgcn_mfma_f32_16x16x32_bf16(a, B[0][kb], acc[mb][0], 0, 0, 0);
      acc[mb][1] = __builtin_amdgcn_mfma_f32_16x16x32_bf16(a, B[1][kb], acc[mb][1], 0, 0, 0);
    }
  }
  float bv0 = bias[32 * w + lr], bv1 = bias[32 * w + 16 + lr];
  for (int mb = 0; mb < 4; ++mb)
    for (int i = 0; i < 4; ++i) {
      int row = r0 + 16 * mb + 4 * q + i;
      if (row < M) {
        long long base = (long long)row * 128 + 32 * w + lr;
        C[base] = acc[mb][0][i] + bv0;
        C[base + 16] = acc[mb][1][i] + bv1;
      }
    }
}

// ---------------------------------------------------------------------------
// Fused edge kernel: 64 edges/block, 4 waves; wave w owns cols [32w,32w+32).
// LDS: sSE + sDE only (~37KB) -> 4 blocks/CU. 7 barriers.
// ---------------------------------------------------------------------------
__global__ __launch_bounds__(256, 4) void edge_fused(
    const unsigned short* __restrict__ src_h, const unsigned short* __restrict__ dst_h,
    const int* __restrict__ edge_src, const int* __restrict__ edge_dst,
    const unsigned short* __restrict__ wT,
    const float* __restrict__ b1, const float* __restrict__ b2,
    const float* __restrict__ b3, const float* __restrict__ ln_g,
    const float* __restrict__ ln_b, const float* __restrict__ bg1,
    const float* __restrict__ Wg2, const float* __restrict__ bg2,
    float* __restrict__ upd, int E) {
  __shared__ __align__(16) unsigned short sSE[64][136];  // se, later h1
  __shared__ __align__(16) unsigned short sDE[64][136];  // de, later h2
  __shared__ int sDst[64];
  __shared__ float sGate[64];
  __shared__ float sR1[4][64];
  __shared__ float sR2[4][64];

  int tid = threadIdx.x;
  int e0 = blockIdx.x * 64;

  {  // gather se/de rows (bf16, 256B each) — 4 threads per edge row
    int r = tid >> 2, seg = tid & 3;
    int e = e0 + r;
    int ee = (e < E) ? e : (E - 1);
    int es = edge_src[ee], ed = edge_dst[ee];
    if (seg == 0) sDst[r] = (e < E) ? ed : -1;
    const int4* ps = (const int4*)(src_h + (long long)es * 128);
    const int4* pd = (const int4*)(dst_h + (long long)ed * 128);
    for (int it = 0; it < 4; ++it) {
      int cc = seg * 4 + it;
      *(int4*)&sSE[r][cc * 8] = ps[cc];
      *(int4*)&sDE[r][cc * 8] = pd[cc];
    }
  }

  int w = tid >> 6, lane = tid & 63, lr = lane & 15, q = lane >> 4;
  const unsigned short* pB = wT + (32 * w + lr) * 128 + q * 8;

  bf16x8 B[2][4];

  auto pass = [&](const unsigned short (*Ab)[136], floatx4 (&acc)[4][2]) {
    for (int kb = 0; kb < 4; ++kb) {
      int k = kb * 32 + q * 8;
      for (int mb = 0; mb < 4; ++mb) {
        bf16x8 a = *(const bf16x8*)&Ab[16 * mb + lr][k];
        acc[mb][0] = __builtin_amdgcn_mfma_f32_16x16x32_bf16(a, B[0][kb], acc[mb][0], 0, 0, 0);
        acc[mb][1] = __builtin_amdgcn_mfma_f32_16x16x32_bf16(a, B[1][kb], acc[mb][1], 0, 0, 0);
      }
    }
  };

  __syncthreads();  // B1: gather visible

  // ---- gate path: accg = se@Wg1a + de@Wg1b ----
  floatx4 accg[4][2];
  for (int mb = 0; mb < 4; ++mb)
    for (int nb = 0; nb < 2; ++nb) accg[mb][nb] = (floatx4){0.f, 0.f, 0.f, 0.f};
  LDB(pB + 6 * 16384, B);
  pass(sSE, accg);
  LDB(pB + 7 * 16384, B);
  pass(sDE, accg);

  {  // partial dot with Wg2 (gelu applied), reduce over lr within each quad
    float wg0 = Wg2[32 * w + lr], wg1 = Wg2[32 * w + 16 + lr];
    float bgv0 = bg1[32 * w + lr], bgv1 = bg1[32 * w + 16 + lr];
    for (int mb = 0; mb < 4; ++mb)
      for (int i = 0; i < 4; ++i) {
        float p = geluf(accg[mb][0][i] + bgv0) * wg0 +
                  geluf(accg[mb][1][i] + bgv1) * wg1;
        p += __shfl_xor(p, 1); p += __shfl_xor(p, 2);
        p += __shfl_xor(p, 4); p += __shfl_xor(p, 8);
        if (lr == 0) sR1[w][16 * mb + 4 * q + i] = p;
      }
  }
  __syncthreads();  // B2: sR1 visible
  if (tid < 64) {
    float g = sR1[0][tid] + sR1[1][tid] + sR1[2][tid] + sR1[3][tid] + bg2[0];
    sGate[tid] = 1.f / (1.f + __expf(-g));  // read only after B5/B7
  }

  // ---- stage 1: h1 = gelu(se@W1a + de@W1b + b1) ----
  floatx4 acc1[4][2];
  for (int mb = 0; mb < 4; ++mb)
    for (int nb = 0; nb < 2; ++nb) acc1[mb][nb] = (floatx4){0.f, 0.f, 0.f, 0.f};
  LDB(pB + 2 * 16384, B);
  pass(sSE, acc1);
  LDB(pB + 3 * 16384, B);
  pass(sDE, acc1);
  __syncthreads();  // B3: all reads of sSE/sDE done
  {
    float bv0 = b1[32 * w + lr], bv1 = b1[32 * w + 16 + lr];
    for (int mb = 0; mb < 4; ++mb)
      for (int i = 0; i < 4; ++i) {
        int r = 16 * mb + 4 * q + i;
        sSE[r][32 * w + lr] = f2bf(geluf(acc1[mb][0][i] + bv0));
        sSE[r][32 * w + 16 + lr] = f2bf(geluf(acc1[mb][1][i] + bv1));
      }
  }
  __syncthreads();  // B4: h1 visible

  // ---- stage 2: h2 = gelu(h1@W2 + b2) ----
  floatx4 acc2[4][2];
  for (int mb = 0; mb < 4; ++mb)
    for (int nb = 0; nb < 2; ++nb) acc2[mb][nb] = (floatx4){0.f, 0.f, 0.f, 0.f};
  LDB(pB + 4 * 16384, B);
  pass(sSE, acc2);
  {  // write h2 into sDE (all sDE reads were before B3)
    float bv0 = b2[32 * w + lr], bv1 = b2[32 * w + 16 + lr];
    for (int mb = 0; mb < 4; ++mb)
      for (int i = 0; i < 4; ++i) {
        int r = 16 * mb + 4 * q + i;
        sDE[r][32 * w + lr] = f2bf(geluf(acc2[mb][0][i] + bv0));
        sDE[r][32 * w + 16 + lr] = f2bf(geluf(acc2[mb][1][i] + bv1));
      }
  }
  __syncthreads();  // B5: h2 visible

  // ---- stage 3: x = h2@W3 + b3 ; layernorm ; gate ; scatter ----
  floatx4 acc3[4][2];
  for (int mb = 0; mb < 4; ++mb)
    for (int nb = 0; nb < 2; ++nb) acc3[mb][nb] = (floatx4){0.f, 0.f, 0.f, 0.f};
  LDB(pB + 5 * 16384, B);
  pass(sDE, acc3);
  {
    float bv0 = b3[32 * w + lr], bv1 = b3[32 * w + 16 + lr];
    for (int mb = 0; mb < 4; ++mb)
      for (int i = 0; i < 4; ++i) {
        float x0 = acc3[mb][0][i] + bv0;
        float x1 = acc3[mb][1][i] + bv1;
        acc3[mb][0][i] = x0; acc3[mb][1][i] = x1;
        float s = x0 + x1, s2 = x0 * x0 + x1 * x1;
        s += __shfl_xor(s, 1); s += __shfl_xor(s, 2);
        s += __shfl_xor(s, 4); s += __shfl_xor(s, 8);
        s2 += __shfl_xor(s2, 1); s2 += __shfl_xor(s2, 2);
        s2 += __shfl_xor(s2, 4); s2 += __shfl_xor(s2, 8);
        if (lr == 0) { sR1[w][16 * mb + 4 * q + i] = s; sR2[w][16 * mb + 4 * q + i] = s2; }
      }
  }
  __syncthreads();  // B6: LN partials visible
  if (tid < 64) {
    float s = sR1[0][tid] + sR1[1][tid] + sR1[2][tid] + sR1[3][tid];
    float s2 = sR2[0][tid] + sR2[1][tid] + sR2[2][tid] + sR2[3][tid];
    float m = s * (1.f / 128.f);
    float v = s2 * (1.f / 128.f) - m * m;
    sR1[0][tid] = m;
    sR2[0][tid] = rsqrtf(v + LN_EPS);
  }
  __syncthreads();  // B7: stats + sGate visible
  {
    float lg0 = ln_g[32 * w + lr], lg1 = ln_g[32 * w + 16 + lr];
    float lb0 = ln_b[32 * w + lr], lb1 = ln_b[32 * w + 16 + lr];
    for (int mb = 0; mb < 4; ++mb)
      for (int i = 0; i < 4; ++i) {
        int r = 16 * mb + 4 * q + i;
        int dst = sDst[r];
        if (dst >= 0) {
          float m = sR1[0][r], rs = sR2[0][r], gt = sGate[r];
          float v0 = ((acc3[mb][0][i] - m) * rs * lg0 + lb0) * gt;
          float v1 = ((acc3[mb][1][i] - m) * rs * lg1 + lb1) * gt;
          float* base = upd + (long long)dst * 128;
          unsafeAtomicAdd(base + 32 * w + lr, v0);
          unsafeAtomicAdd(base + 32 * w + 16 + lr, v1);
        }
      }
  }
}

// ---------------------------------------------------------------------------
extern "C" void kernel_launch(void* const* d_in, const int* in_sizes, int n_in,
                              void* d_out, int out_size, void* d_ws, size_t ws_size,
                              hipStream_t stream) {
  const float* feat   = (const float*)d_in[0];
  const int* edge_src = (const int*)d_in[1];
  const int* edge_dst = (const int*)d_in[2];
  const float* W_src = (const float*)d_in[3];  const float* b_src = (const float*)d_in[4];
  const float* W_dst = (const float*)d_in[5];  const float* b_dst = (const float*)d_in[6];
  const float* W1a = (const float*)d_in[7];    const float* W1b = (const float*)d_in[8];
  const float* b1  = (const float*)d_in[9];
  const float* W2  = (const float*)d_in[10];   const float* b2  = (const float*)d_in[11];
  const float* W3  = (const float*)d_in[12];   const float* b3  = (const float*)d_in[13];
  const float* ln_g = (const float*)d_in[14];  const float* ln_b = (const float*)d_in[15];
  const float* Wg1a = (const float*)d_in[16];  const float* Wg1b = (const float*)d_in[17];
  const float* bg1  = (const float*)d_in[18];
  const float* Wg2  = (const float*)d_in[19];  const float* bg2 = (const float*)d_in[20];
  const float* W_out = (const float*)d_in[21]; const float* b_out = (const float*)d_in[22];

  int N = in_sizes[0] / 128;   // 100000
  int E = in_sizes[1];         // 400000

  // workspace layout (bytes): [wT 9*32KB][src_h bf16][dst_h bf16][upd fp32]
  char* ws = (char*)d_ws;
  unsigned short* wT = (unsigned short*)ws;
  size_t off = 9 * 16384 * sizeof(unsigned short);
  unsigned short* src_h = (unsigned short*)(ws + off);
  off += (size_t)N * 128 * sizeof(unsigned short);
  unsigned short* dst_h = (unsigned short*)(ws + off);
  off += (size_t)N * 128 * sizeof(unsigned short);
  float* upd = (float*)(ws + off);

  (void)hipMemsetAsync(upd, 0, (size_t)N * 128 * sizeof(float), stream);
  prep_weights<<<9, 256, 0, stream>>>(W_src, W_dst, W1a, W1b, W2, W3, Wg1a, Wg1b,
                                      W_out, wT);
  int mtiles = (N + 63) / 64;
  gemm_node<<<mtiles, 256, 0, stream>>>(feat, wT, b_src, b_dst, src_h, dst_h, N);
  edge_fused<<<(E + 63) / 64, 256, 0, stream>>>(src_h, dst_h, edge_src, edge_dst, wT,
                                                b1, b2, b3, ln_g, ln_b, bg1, Wg2, bg2,
                                                upd, E);
  gemm_out<<<mtiles, 256, 0, stream>>>(upd, wT + 8 * 16384, b_out, (float*)d_out, N);
}